// Round 15
// baseline (249.722 us; speedup 1.0000x reference)
//
#include <hip/hip_runtime.h>
#include <float.h>

// Chamfer loss: B=4, N=M=8192, D=3, fp32 in, scalar fp32 out.
// loss = mean_n min_m ||x_n-y_m||^2 + mean_m min_n ||...||^2 + lambda*bpp
//
// R14: EXACT grid nearest-neighbor (algorithmic: O(N*rings) not O(N^2)).
// The pairwise formulation plateaued: FMA path ~44us, MFMA path ~30us
// (R6..R13: occupancy/merge/batching/asm all null or negative).
// Design: 8 grids (2 clouds x 4 batches), 32^3 cells, h=0.33 over
// [-5.28,5.28] (outliers clamped inward - bound stays valid since true
// position is further outward in the clamping dim). Counting sort ->
// per-query Chebyshev ring walk; after finishing ring r, any unsearched
// point is >= r*h away, so stop when best^2 <= (r*h_chk)^2, h_chk<h
// conservative. Hard cap r=31 => full grid => exact. 2 lanes/query
// (dz parity) combined via shfl_xor each ring. Row-contiguous cells
// merge into single [start,end) scans (points sorted by cell id).
// Exact fp32 distances (no bf16 split); min over a fixed multiset is
// order-independent -> deterministic despite atomic scatter order.

#define NPTS   8192
#define NB     4
#define NPTOT  (NB * NPTS)          // 32768 per cloud
#define GN     32
#define GCELLS (GN * GN * GN)       // 32768 cells per grid
#define GB     5.28f
#define INVH   3.0303030303f        // GN / (2*GB), h = 0.33
#define HCHK   0.3299f              // < true h: conservative stop bound

__device__ __forceinline__ int cellc(float v) {
    int i = (int)((v + GB) * INVH);
    return min(max(i, 0), GN - 1);
}

__global__ __launch_bounds__(256) void zero_counts(int4* counts4) {
    counts4[blockIdx.x * 256 + threadIdx.x] = make_int4(0, 0, 0, 0);
}

// i in [0, 2*NPTOT): grid g = i>>13 (cloud*4+b); point offset = i & 32767
__global__ __launch_bounds__(256) void hist(
        const float* __restrict__ X, const float* __restrict__ Y,
        int* __restrict__ counts) {
    int i = blockIdx.x * 256 + threadIdx.x;
    int g = i >> 13;
    int rem = i & (NPTOT - 1);
    const float* src = (i < NPTOT) ? X : Y;
    float x = src[3 * rem], y = src[3 * rem + 1], z = src[3 * rem + 2];
    int cid = (cellc(z) * GN + cellc(y)) * GN + cellc(x);
    atomicAdd(&counts[g * GCELLS + cid], 1);
}

// one block per grid: exclusive scan of 32768 counts -> starts & cursor
__global__ __launch_bounds__(1024) void scan(
        const int* __restrict__ counts, int* __restrict__ starts,
        int* __restrict__ cursor) {
    __shared__ int s[1024];
    int g = blockIdx.x, t = threadIdx.x;
    const int* cb = counts + g * GCELLS;
    int c[32], sum = 0;
#pragma unroll
    for (int j = 0; j < 32; j++) { c[j] = cb[t * 32 + j]; sum += c[j]; }
    s[t] = sum;
    __syncthreads();
    for (int off = 1; off < 1024; off <<= 1) {
        int v = (t >= off) ? s[t - off] : 0;
        __syncthreads();
        s[t] += v;
        __syncthreads();
    }
    int running = s[t] - sum;      // exclusive prefix of this thread's chunk
    int* sb = starts + g * GCELLS;
    int* ub = cursor + g * GCELLS;
#pragma unroll
    for (int j = 0; j < 32; j++) {
        sb[t * 32 + j] = running;
        ub[t * 32 + j] = running;
        running += c[j];
    }
}

__global__ __launch_bounds__(256) void scatter(
        const float* __restrict__ X, const float* __restrict__ Y,
        int* __restrict__ cursor, float4* __restrict__ sorted) {
    int i = blockIdx.x * 256 + threadIdx.x;
    int g = i >> 13;
    int rem = i & (NPTOT - 1);
    const float* src = (i < NPTOT) ? X : Y;
    float x = src[3 * rem], y = src[3 * rem + 1], z = src[3 * rem + 2];
    int cid = (cellc(z) * GN + cellc(y)) * GN + cellc(x);
    int slot = atomicAdd(&cursor[g * GCELLS + cid], 1);
    sorted[(size_t)g * NPTS + slot] = make_float4(x, y, z, 0.0f);
}

// 2 lanes per query (dz parity). q layout: [dir(2)][b(4)][8192].
__global__ __launch_bounds__(256) void nn_kernel(
        const float* __restrict__ X, const float* __restrict__ Y,
        const float4* __restrict__ sorted, const int* __restrict__ starts,
        float* __restrict__ minsD) {
    int tid = blockIdx.x * 256 + threadIdx.x;   // < 131072
    int parity = tid & 1;
    int q = tid >> 1;                            // < 65536
    int dir = q >> 15;
    int rem = q & (NPTOT - 1);
    const float* src = dir ? Y : X;
    float qx = src[3 * rem], qy = src[3 * rem + 1], qz = src[3 * rem + 2];
    int b = rem >> 13;
    int dbg = (1 - dir) * NB + b;               // DB grid = other cloud
    const int* st = starts + (size_t)dbg * GCELLS;
    const float4* pts = sorted + (size_t)dbg * NPTS;

    int qix = cellc(qx), qiy = cellc(qy), qiz = cellc(qz);
    float best = FLT_MAX;

    for (int r = 0; r < GN; r++) {
        for (int dz = -r; dz <= r; dz++) {
            if (((dz + r) & 1) != parity) continue;
            int iz = qiz + dz;
            if ((unsigned)iz >= GN) continue;
            int zedge = (dz == -r) | (dz == r);
            for (int dy = -r; dy <= r; dy++) {
                int iy = qiy + dy;
                if ((unsigned)iy >= GN) continue;
                int rowbase = (iz * GN + iy) * GN;
                if (zedge | (dy == -r) | (dy == r)) {
                    // full row: cells contiguous -> one scan range
                    int x0 = max(qix - r, 0), x1 = min(qix + r, GN - 1);
                    int s = st[rowbase + x0];
                    int e = (rowbase + x1 == GCELLS - 1) ? NPTS
                                                         : st[rowbase + x1 + 1];
                    for (int j = s; j < e; j++) {
                        float4 p = pts[j];
                        float ax = qx - p.x, ay = qy - p.y, az = qz - p.z;
                        float d = __fmaf_rn(az, az,
                                  __fmaf_rn(ay, ay, ax * ax));
                        best = fminf(best, d);
                    }
                } else {
                    // interior row: only dx = -r and +r
#pragma unroll
                    for (int k = 0; k < 2; k++) {
                        int ix = qix + (k ? r : -r);
                        if ((unsigned)ix >= GN) continue;
                        int cid = rowbase + ix;
                        int s = st[cid];
                        int e = (cid == GCELLS - 1) ? NPTS : st[cid + 1];
                        for (int j = s; j < e; j++) {
                            float4 p = pts[j];
                            float ax = qx - p.x, ay = qy - p.y, az = qz - p.z;
                            float d = __fmaf_rn(az, az,
                                      __fmaf_rn(ay, ay, ax * ax));
                            best = fminf(best, d);
                        }
                    }
                }
            }
        }
        // combine parity partners; stop when no unsearched point can win
        float ob = __shfl_xor(best, 1, 64);
        best = fminf(best, ob);
        float rd = (float)r * HCHK;
        if (best <= rd * rd) break;
    }
    if (parity == 0) minsD[q] = best;
}

__global__ __launch_bounds__(1024) void finale(
        const float* __restrict__ minsD,
        const float* __restrict__ bpp, const float* __restrict__ lam,
        float* __restrict__ out) {
    __shared__ float s1[1024], s2[1024];
    int t = threadIdx.x;
    float sx = 0.f, sy = 0.f;
    for (int i = t; i < NPTOT; i += 1024) {
        sx += minsD[i];
        sy += minsD[NPTOT + i];
    }
    s1[t] = sx; s2[t] = sy;
    __syncthreads();
    for (int h = 512; h > 0; h >>= 1) {
        if (t < h) { s1[t] += s1[t + h]; s2[t] += s2[t + h]; }
        __syncthreads();
    }
    if (t == 0) {
        const float inv = 1.0f / (float)NPTOT;
        out[0] = (s1[0] + s2[0]) * inv + lam[0] * bpp[0];
    }
}

extern "C" void kernel_launch(void* const* d_in, const int* in_sizes, int n_in,
                              void* d_out, int out_size, void* d_ws, size_t ws_size,
                              hipStream_t stream) {
    const float* X   = (const float*)d_in[0];   // pc_pred  [4,8192,3]
    const float* Y   = (const float*)d_in[1];   // pc_target[4,8192,3]
    const float* bpp = (const float*)d_in[2];
    const float* lam = (const float*)d_in[3];
    float* out = (float*)d_out;

    char* w = (char*)d_ws;
    float4* sorted = (float4*)w;                w += (size_t)8 * NPTS * sizeof(float4);
    int*    counts = (int*)w;                   w += (size_t)8 * GCELLS * sizeof(int);
    int*    starts = (int*)w;                   w += (size_t)8 * GCELLS * sizeof(int);
    int*    cursor = (int*)w;                   w += (size_t)8 * GCELLS * sizeof(int);
    float*  minsD  = (float*)w;

    zero_counts<<<256, 256, 0, stream>>>((int4*)counts);
    hist<<<256, 256, 0, stream>>>(X, Y, counts);
    scan<<<8, 1024, 0, stream>>>(counts, starts, cursor);
    scatter<<<256, 256, 0, stream>>>(X, Y, cursor, sorted);
    nn_kernel<<<512, 256, 0, stream>>>(X, Y, sorted, starts, minsD);
    finale<<<1, 1024, 0, stream>>>(minsD, bpp, lam, out);
}

// Round 16
// 40.567 us; speedup vs baseline: 6.1557x; 6.1557x over previous
//
#include <hip/hip_runtime.h>

// Chamfer loss: B=4, N=M=8192, D=3, fp32 in, scalar fp32 out.
// loss = mean_n min_m ||x_n-y_m||^2 + mean_m min_n ||...||^2 + lambda*bpp
//
// R15 = R12's verified loop (best: 40.6us total) with K=8 math and 16B
// B-records (was K=11, 32B). Rows use plain bf16 queries a=bf16(x); the
// kernel computes min_y ||a-y||^2 EXACTLY (y kept exact via hi/lo and
// n2 hi/lo); reduce1 adds ||a||^2 consistently. Query perturbation
// ||a-x|| <= 2^-8||x|| enters the mean with random sign -> ~1e-4 final
// error (threshold 5.7e-3). P = n2 - 2 a.y in ONE k-octet:
//   k0-2: -2a_d*yhi_d  k3-5: -2a_d*ylo_d  k6: 1*n2hi  k7: 1*n2lo
// A-frag: lanes 0-31 real octet, lanes 32-63 ZERO (k8-15 contribute 0);
// B loads: all lanes read record (lane&31) -> 512B unique/tile (halved).
// C/D layout unchanged: col=lane&31, row=(q&3)+8*(q>>2)+4*(lane>>5).
// Structure identical to R12: grid 1024 (pass2 x b4 x rowblk64 x seg2),
// 4 waves/block, wave = 32 rows x 4096-pt segment = 128 tiles, 4-tile
// ping-pong groups, paired v_min3 merge (<=2 acc tiles live).

typedef float  f16v __attribute__((ext_vector_type(16)));
typedef short  s8   __attribute__((ext_vector_type(8)));

#define NPTS   8192
#define NB     4
#define NPTOT  (NB * NPTS)        // 32768 points per cloud
#define NSEG   2                  // column-segment split (4096 cols each)
#define RBLK   128

__device__ __forceinline__ ushort f2bf(float f) {
    uint u = __float_as_uint(f);
    u += 0x7FFF + ((u >> 16) & 1);          // round-to-nearest-even
    return (ushort)(u >> 16);
}
__device__ __forceinline__ float bf2f(ushort h) {
    return __uint_as_float(((uint)h) << 16);
}
__device__ __forceinline__ uint pk(ushort lo, ushort hi) {
    return (uint)lo | ((uint)hi << 16);
}

// prep: per point i (both clouds): one 16B A-record and one 16B B-record.
__global__ __launch_bounds__(256) void prep(
        const float* __restrict__ X, const float* __restrict__ Y,
        uint4* __restrict__ Arec, uint4* __restrict__ Brec) {
    int i = blockIdx.x * 256 + threadIdx.x;
    if (i >= 2 * NPTOT) return;
    const float* src = (i < NPTOT) ? X : Y;
    int p = i & (NPTOT - 1);
    float x0 = src[3*p], x1 = src[3*p+1], x2 = src[3*p+2];

    // A-side: a = bf16(x), -2a exact in bf16
    ushort a0 = f2bf(x0), a1 = f2bf(x1), a2 = f2bf(x2);
    float f0 = bf2f(a0), f1 = bf2f(a1), f2v = bf2f(a2);
    ushort m0 = f2bf(-2.0f * f0), m1 = f2bf(-2.0f * f1), m2 = f2bf(-2.0f * f2v);
    const ushort ONE = 0x3F80;
    Arec[i] = make_uint4(pk(m0, m1), pk(m2, m0), pk(m1, m2), pk(ONE, ONE));

    // B-side: y exact via hi/lo; n2 = ||y||^2 via hi/lo
    ushort l0 = f2bf(x0 - f0), l1 = f2bf(x1 - f1), l2 = f2bf(x2 - f2v);
    float n2 = __fmaf_rn(x0, x0, __fmaf_rn(x1, x1, x2 * x2));
    ushort nh = f2bf(n2);
    ushort nl = f2bf(n2 - bf2f(nh));
    Brec[i] = make_uint4(pk(a0, a1), pk(a2, l0), pk(l1, l2), pk(nh, nl));
}

#define LOADG(G, g)                                                        \
    _Pragma("unroll")                                                      \
    for (int u = 0; u < 4; u++)                                            \
        G[u] = *(const s8*)(Bseg + (size_t)((g) * 4 + u) * 32 + bcol);

// paired merge: 2 MFMAs then 16 min3 (2 acc tiles live, 32 regs max)
#define COMPG(G)                                                           \
    _Pragma("unroll")                                                      \
    for (int u = 0; u < 4; u += 2) {                                       \
        f16v acc0 = __builtin_amdgcn_mfma_f32_32x32x16_bf16(               \
            afrag, G[u], zero16, 0, 0, 0);                                 \
        f16v acc1 = __builtin_amdgcn_mfma_f32_32x32x16_bf16(               \
            afrag, G[u + 1], zero16, 0, 0, 0);                             \
        _Pragma("unroll")                                                  \
        for (int q = 0; q < 16; q++)                                       \
            racc[q] = fminf(fminf(acc0[q], acc1[q]), racc[q]);             \
    }

__global__ __launch_bounds__(256) void mfma_pass(
        const uint4* __restrict__ Arec, const uint4* __restrict__ Brec,
        float* __restrict__ minsP) {
    // grid = 1024: pass(2) x batch(4) x rowblk(64) x seg(2)
    // block = 4 waves; wave owns 32 rows x one 4096-col segment
    int bid  = blockIdx.x;
    int pass = bid >> 9;            // 0: rows=X cols=Y; 1: rows=Y cols=X
    int r    = bid & 511;
    int b    = r >> 7;
    int rem  = r & 127;
    int blk  = rem >> 1;
    int seg  = rem & 1;
    int lane = threadIdx.x & 63;
    int wave = threadIdx.x >> 6;
    int ca   = pass;                // A-cloud: 0=X,1=Y
    int cb   = 1 - pass;
    int ibase = (blk * 4 + wave) * 32;

    const s8 zf = {0, 0, 0, 0, 0, 0, 0, 0};

    // A fragment: lanes 0-31 real (row = lane&31), lanes 32-63 zero octet
    int pA = b * NPTS + ibase + (lane & 31);
    s8 afrag = (lane < 32)
        ? *(const s8*)&Arec[(size_t)ca * NPTOT + pA] : zf;

    // B segment: 4096 points = 128 col-tiles of 32 records (16B each)
    const uint4* Bseg = Brec + (size_t)cb * NPTOT + (size_t)b * NPTS
                      + (size_t)seg * 4096;
    int bcol = lane & 31;           // lanes 32-63 duplicate (A side is 0)

    const f16v zero16 = {0,0,0,0,0,0,0,0,0,0,0,0,0,0,0,0};
    f16v racc;
#pragma unroll
    for (int q = 0; q < 16; q++) racc[q] = 3.0e38f;

    // 32 groups of 4 col-tiles, ping-pong prefetch
    s8 GA[4], GB[4];
    LOADG(GA, 0);
    for (int g = 0; g < 30; g += 2) {
        LOADG(GB, g + 1);
        COMPG(GA);
        LOADG(GA, g + 2);
        COMPG(GB);
    }
    LOADG(GB, 31);
    COMPG(GA);
    COMPG(GB);

    // row-min across the 32 cols (lane bits 0-4), rows stay fixed
#pragma unroll
    for (int q = 0; q < 16; q++) {
        float v = racc[q];
        v = fminf(v, __shfl_xor(v, 1, 64));
        v = fminf(v, __shfl_xor(v, 2, 64));
        v = fminf(v, __shfl_xor(v, 4, 64));
        v = fminf(v, __shfl_xor(v, 8, 64));
        v = fminf(v, __shfl_xor(v, 16, 64));
        racc[q] = v;
    }
    if ((lane & 31) == 0) {
        float* dst = minsP + ((size_t)seg * 2 + pass) * NPTOT
                   + (size_t)b * NPTS + ibase;
        int half = lane >> 5;       // row offset +4 for lanes 32..63
#pragma unroll
        for (int q = 0; q < 16; q++)
            dst[(q & 3) + 8 * (q >> 2) + 4 * half] = racc[q];
    }
}

__global__ __launch_bounds__(256) void reduce1(
        const float* __restrict__ minsP,
        const float* __restrict__ X, const float* __restrict__ Y,
        float2* __restrict__ out2) {
    __shared__ float s1[256], s2[256];
    int t = threadIdx.x;
    int i = blockIdx.x * 256 + t;           // RBLK*256 == NPTOT exactly
    float mx = 3.0e38f, my = 3.0e38f;
#pragma unroll
    for (int s = 0; s < NSEG; s++) {
        mx = fminf(mx, minsP[((size_t)s * 2 + 0) * NPTOT + i]);
        my = fminf(my, minsP[((size_t)s * 2 + 1) * NPTOT + i]);
    }
    // add ||a||^2 with a = bf16-rounded query coords (consistent with MFMA)
    float a = bf2f(f2bf(X[3*i]));
    float bb = bf2f(f2bf(X[3*i+1]));
    float c = bf2f(f2bf(X[3*i+2]));
    float sx = mx + __fmaf_rn(a, a, __fmaf_rn(bb, bb, c * c));
    float d = bf2f(f2bf(Y[3*i]));
    float e = bf2f(f2bf(Y[3*i+1]));
    float f = bf2f(f2bf(Y[3*i+2]));
    float sy = my + __fmaf_rn(d, d, __fmaf_rn(e, e, f * f));
    s1[t] = sx; s2[t] = sy;
    __syncthreads();
    for (int s = 128; s > 0; s >>= 1) {
        if (t < s) { s1[t] += s1[t + s]; s2[t] += s2[t + s]; }
        __syncthreads();
    }
    if (t == 0) out2[blockIdx.x] = make_float2(s1[0], s2[0]);
}

__global__ __launch_bounds__(RBLK) void reduce2(
        const float2* __restrict__ p2,
        const float* __restrict__ bpp, const float* __restrict__ lam,
        float* __restrict__ out) {
    __shared__ float s[RBLK];
    int t = threadIdx.x;
    float2 p = p2[t];
    s[t] = p.x + p.y;
    __syncthreads();
    for (int h = RBLK / 2; h > 0; h >>= 1) {
        if (t < h) s[t] += s[t + h];
        __syncthreads();
    }
    if (t == 0) out[0] = s[0] * (1.0f / (float)NPTOT) + lam[0] * bpp[0];
}

extern "C" void kernel_launch(void* const* d_in, const int* in_sizes, int n_in,
                              void* d_out, int out_size, void* d_ws, size_t ws_size,
                              hipStream_t stream) {
    const float* X   = (const float*)d_in[0];   // pc_pred  [4,8192,3]
    const float* Y   = (const float*)d_in[1];   // pc_target[4,8192,3]
    const float* bpp = (const float*)d_in[2];
    const float* lam = (const float*)d_in[3];
    float* out = (float*)d_out;

    char* w = (char*)d_ws;
    float2* p2    = (float2*)w;                 w += 1024;
    float*  minsP = (float*)w;                  w += (size_t)NSEG * 2 * NPTOT * sizeof(float);
    uint4*  Arec  = (uint4*)w;                  w += (size_t)2 * NPTOT * sizeof(uint4);
    uint4*  Brec  = (uint4*)w;

    prep<<<(2 * NPTOT + 255) / 256, 256, 0, stream>>>(X, Y, Arec, Brec);
    mfma_pass<<<1024, 256, 0, stream>>>(Arec, Brec, minsP);
    reduce1<<<RBLK, 256, 0, stream>>>(minsP, X, Y, p2);
    reduce2<<<1, RBLK, 0, stream>>>(p2, bpp, lam, out);
}